// Round 1
// baseline (290.060 us; speedup 1.0000x reference)
//
#include <hip/hip_runtime.h>
#include <hip/hip_bf16.h>
#include <stdint.h>

// ---------- types ----------
typedef __bf16 bf16x8_t __attribute__((ext_vector_type(8)));
typedef float  f32x4_t  __attribute__((ext_vector_type(4)));
typedef short  short8_t __attribute__((ext_vector_type(8)));

__device__ __forceinline__ unsigned short f2b(float f) {
    union { float f; unsigned u; } v; v.f = f;
    unsigned u = v.u;
    return (unsigned short)((u + 0x7FFFu + ((u >> 16) & 1u)) >> 16);
}

#define AS3(p) ((__attribute__((address_space(3))) void*)(p))
#define AS1(p) ((const __attribute__((address_space(1))) void*)(p))

// ---------- constants ----------
#define NB   16
#define CIN  512
#define MMID 256
#define HW   4096

// ---------- weight prep: fp32 -> bf16, stack state+proj ----------
__global__ __launch_bounds__(256) void prep_weights(
    const float* __restrict__ Ws, const float* __restrict__ Wp,
    const float* __restrict__ Wef, const float* __restrict__ bs,
    const float* __restrict__ bp,
    unsigned short* __restrict__ Wsp, unsigned short* __restrict__ Wex,
    float* __restrict__ bsp)
{
    int i = blockIdx.x * 256 + threadIdx.x;   // grid 512 blocks -> 131072 threads
    if (i < MMID * CIN) {
        Wsp[i]              = f2b(Ws[i]);     // rows 0..255 = W_state
        Wsp[MMID * CIN + i] = f2b(Wp[i]);     // rows 256..511 = W_proj
        Wex[i]              = f2b(Wef[i]);    // 512*256
    }
    if (i < MMID) { bsp[i] = bs[i]; bsp[MMID + i] = bp[i]; }
}

// ---------- x [n][512][4096] f32 -> xT [n][4096][512] bf16 ----------
__global__ __launch_bounds__(256) void transpose_convert_x(
    const float* __restrict__ x, unsigned short* __restrict__ xT)
{
    __shared__ unsigned short tile[64][66];
    const int n = blockIdx.z, c0 = blockIdx.y * 64, h0 = blockIdx.x * 64;
    const float* s = x + ((size_t)n * CIN + c0) * HW + h0;
    unsigned short* d = xT + ((size_t)n * HW + h0) * CIN + c0;
    const int t = threadIdx.x;
    {   // read: 16 rows (channels) per pass, 16 threads * float4 across h
        const int rr = t >> 4, cc = (t & 15) * 4;
        #pragma unroll
        for (int p = 0; p < 4; ++p) {
            int r = p * 16 + rr;
            float4 v = *(const float4*)(s + (size_t)r * HW + cc);
            tile[r][cc + 0] = f2b(v.x); tile[r][cc + 1] = f2b(v.y);
            tile[r][cc + 2] = f2b(v.z); tile[r][cc + 3] = f2b(v.w);
        }
    }
    __syncthreads();
    {   // write: rows h, 8 bf16 along c per thread
        const int wr = t >> 3, wc = (t & 7) * 8;
        #pragma unroll
        for (int p = 0; p < 2; ++p) {
            int h = p * 32 + wr;
            unsigned short tmp[8];
            #pragma unroll
            for (int j = 0; j < 8; ++j) tmp[j] = tile[wc + j][h];
            *(short8_t*)(d + (size_t)h * CIN + wc) = *(const short8_t*)tmp;
        }
    }
}

// ---------- generic bf16 64x64-tile transpose: src[R][C] -> dst[C][R] ----------
__global__ __launch_bounds__(256) void transpose_bf16_64(
    const unsigned short* __restrict__ src, unsigned short* __restrict__ dst,
    int srs, int drs, long long sbs, long long dbs)
{
    __shared__ unsigned short tile[64][66];
    const int n = blockIdx.z, r0 = blockIdx.y * 64, c0 = blockIdx.x * 64;
    const unsigned short* s = src + (size_t)n * sbs + (size_t)r0 * srs + c0;
    unsigned short* d = dst + (size_t)n * dbs + (size_t)c0 * drs + r0;
    const int t = threadIdx.x;
    const int rr = t >> 3, cc = (t & 7) * 8;
    #pragma unroll
    for (int p = 0; p < 2; ++p) {
        int r = p * 32 + rr;
        short8_t v = *(const short8_t*)(s + (size_t)r * srs + cc);
        #pragma unroll
        for (int j = 0; j < 8; ++j) tile[r][cc + j] = ((const unsigned short*)&v)[j];
    }
    __syncthreads();
    #pragma unroll
    for (int p = 0; p < 2; ++p) {
        int c = p * 32 + rr;       // dst row (src col)
        unsigned short tmp[8];
        #pragma unroll
        for (int j = 0; j < 8; ++j) tmp[j] = tile[cc + j][c];
        *(short8_t*)(d + (size_t)c * drs + cc) = *(const short8_t*)tmp;
    }
}

// ---------- softmax over rows of scores (scale 1/64 folded in) ----------
__global__ __launch_bounds__(64) void softmax_rows(
    const float* __restrict__ scores, unsigned short* __restrict__ attn)
{
    const size_t row = blockIdx.x;            // n*256 + m
    const float* s = scores + row * 256;
    const int l = threadIdx.x;
    float4 v = *(const float4*)(s + l * 4);
    float mx = fmaxf(fmaxf(v.x, v.y), fmaxf(v.z, v.w));
    #pragma unroll
    for (int off = 32; off; off >>= 1) mx = fmaxf(mx, __shfl_xor(mx, off));
    const float sc = 0.015625f;               // 1/64
    float e0 = __expf((v.x - mx) * sc), e1 = __expf((v.y - mx) * sc);
    float e2 = __expf((v.z - mx) * sc), e3 = __expf((v.w - mx) * sc);
    float sum = e0 + e1 + e2 + e3;
    #pragma unroll
    for (int off = 32; off; off >>= 1) sum += __shfl_xor(sum, off);
    const float inv = 1.0f / sum;
    unsigned short o[4] = { f2b(e0 * inv), f2b(e1 * inv), f2b(e2 * inv), f2b(e3 * inv) };
    *(uint64_t*)(attn + row * 256 + l * 4) = *(const uint64_t*)o;
}

// ---------- NT GEMM: D[m][n] = sum_k A[m][k] * B[n][k]  (both k-contiguous) ----------
// 128x128 tile, 4 waves (2x2), BK=64, mfma_f32_16x16x32_bf16, global_load_lds staging.
// EPI: 0 = +bias[row], bf16 store; 1 = f32 store; 2 = bf16 store; 3 = +bias[row]+resid, f32 store
template <int EPI>
__global__ __launch_bounds__(256) void gemm_nt(
    const unsigned short* __restrict__ A, const unsigned short* __restrict__ B,
    int lda, int ldb, int K,
    long long strideA, long long strideB,
    const float* __restrict__ bias,
    const float* __restrict__ resid,
    void* __restrict__ Cout, int ldc, long long strideC)
{
    __shared__ unsigned short As[128 * 64];
    __shared__ unsigned short Bs[128 * 64];

    const int n  = blockIdx.z;
    const int m0 = blockIdx.y * 128;
    const int n0 = blockIdx.x * 128;

    const unsigned short* Ab = A + (size_t)n * strideA + (size_t)m0 * lda;
    const unsigned short* Bb = B + (size_t)n * strideB + (size_t)n0 * ldb;

    const int t    = threadIdx.x;
    const int lane = t & 63;
    const int wave = t >> 6;
    const int wr   = (wave >> 1) * 64;
    const int wc   = (wave & 1) * 64;
    const int l15  = lane & 15;
    const int l16  = lane >> 4;

    f32x4_t acc[4][4] = {};

    for (int k0 = 0; k0 < K; k0 += 64) {
        #pragma unroll
        for (int c = 0; c < 4; ++c) {
            const int o   = (c * 256 + t) * 16;   // byte offset in 16KB tile
            const int row = o >> 7;               // 128B per row (64 bf16)
            const int ce  = (o & 127) >> 1;       // element offset within row
            __builtin_amdgcn_global_load_lds(
                AS1(Ab + (size_t)row * lda + k0 + ce), AS3((char*)As + o), 16, 0, 0);
            __builtin_amdgcn_global_load_lds(
                AS1(Bb + (size_t)row * ldb + k0 + ce), AS3((char*)Bs + o), 16, 0, 0);
        }
        asm volatile("s_waitcnt vmcnt(0)" ::: "memory");
        __syncthreads();

        #pragma unroll
        for (int ks = 0; ks < 2; ++ks) {
            bf16x8_t af[4], bfr[4];
            const int kb = ks * 32 + l16 * 8;
            #pragma unroll
            for (int i = 0; i < 4; ++i) {
                af[i]  = *(const bf16x8_t*)(As + (wr + i * 16 + l15) * 64 + kb);
                bfr[i] = *(const bf16x8_t*)(Bs + (wc + i * 16 + l15) * 64 + kb);
            }
            #pragma unroll
            for (int i = 0; i < 4; ++i)
                #pragma unroll
                for (int j = 0; j < 4; ++j)
                    acc[i][j] = __builtin_amdgcn_mfma_f32_16x16x32_bf16(af[i], bfr[j], acc[i][j], 0, 0, 0);
        }
        __syncthreads();
    }

    // epilogue: C/D layout col = lane&15, row = (lane>>4)*4 + r  [m89-verified]
    const int colb = n0 + wc + l15;
    const int rowb = m0 + wr + l16 * 4;
    #pragma unroll
    for (int i = 0; i < 4; ++i) {
        #pragma unroll
        for (int r = 0; r < 4; ++r) {
            const int row = rowb + i * 16 + r;
            float badd = 0.f;
            if constexpr (EPI == 0 || EPI == 3) badd = bias[row];
            #pragma unroll
            for (int j = 0; j < 4; ++j) {
                const int col = colb + j * 16;
                float v = acc[i][j][r] + badd;
                const size_t idx = (size_t)n * strideC + (size_t)row * ldc + col;
                if constexpr (EPI == 3) {
                    ((float*)Cout)[idx] = v + resid[idx];
                } else if constexpr (EPI == 1) {
                    ((float*)Cout)[idx] = v;
                } else {
                    ((unsigned short*)Cout)[idx] = f2b(v);
                }
            }
        }
    }
}

// ---------- launch ----------
extern "C" void kernel_launch(void* const* d_in, const int* in_sizes, int n_in,
                              void* d_out, int out_size, void* d_ws, size_t ws_size,
                              hipStream_t stream)
{
    const float* x   = (const float*)d_in[0];
    const float* Ws  = (const float*)d_in[1];
    const float* bs  = (const float*)d_in[2];
    const float* Wp  = (const float*)d_in[3];
    const float* bp  = (const float*)d_in[4];
    const float* Wef = (const float*)d_in[5];
    const float* be  = (const float*)d_in[6];
    float* out = (float*)d_out;

    // workspace carve-up (bf16 tensors first, then fp32)
    unsigned short* xT     = (unsigned short*)d_ws;                       // [16][4096][512]
    unsigned short* Ysp    = xT     + (size_t)NB * HW * CIN;              // [16][512][4096] (state|proj)
    unsigned short* xprojT = Ysp    + (size_t)NB * CIN * HW;              // [16][4096][256]
    unsigned short* xrstT  = xprojT + (size_t)NB * HW * MMID;             // [16][4096][256]
    unsigned short* Wsp    = xrstT  + (size_t)NB * HW * MMID;             // [512][512]
    unsigned short* Wex    = Wsp    + (size_t)CIN * CIN;                  // [512][256]
    unsigned short* attn   = Wex    + (size_t)CIN * MMID;                 // [16][256][256]
    float* scores = (float*)(attn + (size_t)NB * MMID * MMID);            // [16][256][256]
    float* bsp    = scores + (size_t)NB * MMID * MMID;                    // [512]

    prep_weights<<<512, 256, 0, stream>>>(Ws, Wp, Wef, bs, bp, Wsp, Wex, bsp);

    // x -> xT (bf16, transposed to [h][c])
    transpose_convert_x<<<dim3(HW / 64, CIN / 64, NB), 256, 0, stream>>>(x, xT);

    // Ysp[mm][h] = Wsp[mm][c] . xT[h][c] + bsp[mm]   (M=512, N=4096, K=512)
    gemm_nt<0><<<dim3(HW / 128, CIN / 128, NB), 256, 0, stream>>>(
        Wsp, xT, CIN, CIN, CIN, 0LL, (long long)HW * CIN,
        bsp, nullptr, Ysp, HW, (long long)CIN * HW);

    // x_projT[h][k] = transpose of Ysp proj half
    transpose_bf16_64<<<dim3(HW / 64, MMID / 64, NB), 256, 0, stream>>>(
        Ysp + (size_t)MMID * HW, xprojT, HW, MMID,
        (long long)CIN * HW, (long long)HW * MMID);

    // scores[m][k] = x_state[m][h] . x_proj[k][h]   (M=N=256, K=4096)
    gemm_nt<1><<<dim3(MMID / 128, MMID / 128, NB), 256, 0, stream>>>(
        Ysp, Ysp + (size_t)MMID * HW, HW, HW, HW,
        (long long)CIN * HW, (long long)CIN * HW,
        nullptr, nullptr, scores, MMID, (long long)MMID * MMID);

    // attn = softmax(scores / 64) rows, bf16
    softmax_rows<<<NB * MMID, 64, 0, stream>>>(scores, attn);

    // x_rstateT[h][m] = x_projT[h][k] . attn[m][k]   (M=4096, N=256, K=256)
    gemm_nt<2><<<dim3(MMID / 128, HW / 128, NB), 256, 0, stream>>>(
        xprojT, attn, MMID, MMID, MMID,
        (long long)HW * MMID, (long long)MMID * MMID,
        nullptr, nullptr, xrstT, MMID, (long long)HW * MMID);

    // out[c][h] = Wex[c][m] . x_rstateT[h][m] + be[c] + x[c][h]   (M=512, N=4096, K=256)
    gemm_nt<3><<<dim3(HW / 128, CIN / 128, NB), 256, 0, stream>>>(
        Wex, xrstT, MMID, MMID, MMID,
        0LL, (long long)HW * MMID,
        be, x, out, HW, (long long)CIN * HW);
}

// Round 2
// 225.483 us; speedup vs baseline: 1.2864x; 1.2864x over previous
//
#include <hip/hip_runtime.h>
#include <hip/hip_bf16.h>
#include <stdint.h>

// ---------- types ----------
typedef __bf16 bf16x8_t __attribute__((ext_vector_type(8)));
typedef float  f32x4_t  __attribute__((ext_vector_type(4)));
typedef short  short8_t __attribute__((ext_vector_type(8)));

__device__ __forceinline__ unsigned short f2b(float f) {
    union { float f; unsigned u; } v; v.f = f;
    unsigned u = v.u;
    return (unsigned short)((u + 0x7FFFu + ((u >> 16) & 1u)) >> 16);
}

#define AS3(p) ((__attribute__((address_space(3))) void*)(p))
#define AS1(p) ((const __attribute__((address_space(1))) void*)(p))

// ---------- constants ----------
#define NB   16
#define CIN  512
#define MMID 256
#define HW   4096
#define KSPLIT 8          // split-K factor for scores GEMM

// ---------- weight prep: fp32 -> bf16, stack state+proj ----------
__global__ __launch_bounds__(256) void prep_weights(
    const float* __restrict__ Ws, const float* __restrict__ Wp,
    const float* __restrict__ Wef, const float* __restrict__ bs,
    const float* __restrict__ bp,
    unsigned short* __restrict__ Wsp, unsigned short* __restrict__ Wex,
    float* __restrict__ bsp)
{
    int i = blockIdx.x * 256 + threadIdx.x;
    if (i < MMID * CIN) {
        Wsp[i]              = f2b(Ws[i]);     // rows 0..255 = W_state
        Wsp[MMID * CIN + i] = f2b(Wp[i]);     // rows 256..511 = W_proj
        Wex[i]              = f2b(Wef[i]);    // 512*256
    }
    if (i < MMID) { bsp[i] = bs[i]; bsp[MMID + i] = bp[i]; }
}

// ---------- x [n][512][4096] f32 -> xT [n][4096][512] bf16 ----------
__global__ __launch_bounds__(256) void transpose_convert_x(
    const float* __restrict__ x, unsigned short* __restrict__ xT)
{
    __shared__ unsigned short tile[64][66];
    const int n = blockIdx.z, c0 = blockIdx.y * 64, h0 = blockIdx.x * 64;
    const float* s = x + ((size_t)n * CIN + c0) * HW + h0;
    unsigned short* d = xT + ((size_t)n * HW + h0) * CIN + c0;
    const int t = threadIdx.x;
    {
        const int rr = t >> 4, cc = (t & 15) * 4;
        #pragma unroll
        for (int p = 0; p < 4; ++p) {
            int r = p * 16 + rr;
            float4 v = *(const float4*)(s + (size_t)r * HW + cc);
            tile[r][cc + 0] = f2b(v.x); tile[r][cc + 1] = f2b(v.y);
            tile[r][cc + 2] = f2b(v.z); tile[r][cc + 3] = f2b(v.w);
        }
    }
    __syncthreads();
    {
        const int wr = t >> 3, wc = (t & 7) * 8;
        #pragma unroll
        for (int p = 0; p < 2; ++p) {
            int h = p * 32 + wr;
            unsigned short tmp[8];
            #pragma unroll
            for (int j = 0; j < 8; ++j) tmp[j] = tile[wc + j][h];
            *(short8_t*)(d + (size_t)h * CIN + wc) = *(const short8_t*)tmp;
        }
    }
}

// ---------- generic bf16 64x64-tile transpose: src[R][C] -> dst[C][R] ----------
__global__ __launch_bounds__(256) void transpose_bf16_64(
    const unsigned short* __restrict__ src, unsigned short* __restrict__ dst,
    int srs, int drs, long long sbs, long long dbs)
{
    __shared__ unsigned short tile[64][66];
    const int n = blockIdx.z, r0 = blockIdx.y * 64, c0 = blockIdx.x * 64;
    const unsigned short* s = src + (size_t)n * sbs + (size_t)r0 * srs + c0;
    unsigned short* d = dst + (size_t)n * dbs + (size_t)c0 * drs + r0;
    const int t = threadIdx.x;
    const int rr = t >> 3, cc = (t & 7) * 8;
    #pragma unroll
    for (int p = 0; p < 2; ++p) {
        int r = p * 32 + rr;
        short8_t v = *(const short8_t*)(s + (size_t)r * srs + cc);
        #pragma unroll
        for (int j = 0; j < 8; ++j) tile[r][cc + j] = ((const unsigned short*)&v)[j];
    }
    __syncthreads();
    #pragma unroll
    for (int p = 0; p < 2; ++p) {
        int c = p * 32 + rr;
        unsigned short tmp[8];
        #pragma unroll
        for (int j = 0; j < 8; ++j) tmp[j] = tile[cc + j][c];
        *(short8_t*)(d + (size_t)c * drs + cc) = *(const short8_t*)tmp;
    }
}

// ---------- scores GEMM, split-K: partials[kc][n][m][k] ----------
// scores[m][k] = sum_h state[m][h] * proj[k][h]; K=4096 split into 8 chunks of 512.
__global__ __launch_bounds__(256) void gemm_scores(
    const unsigned short* __restrict__ Ysp, float* __restrict__ scoresP)
{
    __shared__ unsigned short As[128 * 64];
    __shared__ unsigned short Bs[128 * 64];

    const int z  = blockIdx.z;
    const int n  = z >> 3;
    const int kc = z & 7;
    const int m0 = blockIdx.y * 128;
    const int n0 = blockIdx.x * 128;

    const unsigned short* Ab = Ysp + (size_t)n * CIN * HW + (size_t)m0 * HW;           // state rows
    const unsigned short* Bb = Ysp + (size_t)n * CIN * HW + (size_t)(MMID + n0) * HW;  // proj rows

    const int t    = threadIdx.x;
    const int lane = t & 63;
    const int wave = t >> 6;
    const int wr   = (wave >> 1) * 64;
    const int wc   = (wave & 1) * 64;
    const int l15  = lane & 15;
    const int l16  = lane >> 4;

    f32x4_t acc[4][4] = {};

    const int kbeg = kc * (HW / KSPLIT);
    for (int k0 = kbeg; k0 < kbeg + HW / KSPLIT; k0 += 64) {
        #pragma unroll
        for (int c = 0; c < 4; ++c) {
            const int o   = (c * 256 + t) * 16;
            const int row = o >> 7;
            const int ce  = (o & 127) >> 1;
            __builtin_amdgcn_global_load_lds(
                AS1(Ab + (size_t)row * HW + k0 + ce), AS3((char*)As + o), 16, 0, 0);
            __builtin_amdgcn_global_load_lds(
                AS1(Bb + (size_t)row * HW + k0 + ce), AS3((char*)Bs + o), 16, 0, 0);
        }
        asm volatile("s_waitcnt vmcnt(0)" ::: "memory");
        __syncthreads();

        #pragma unroll
        for (int ks = 0; ks < 2; ++ks) {
            bf16x8_t af[4], bfr[4];
            const int kb = ks * 32 + l16 * 8;
            #pragma unroll
            for (int i = 0; i < 4; ++i) {
                af[i]  = *(const bf16x8_t*)(As + (wr + i * 16 + l15) * 64 + kb);
                bfr[i] = *(const bf16x8_t*)(Bs + (wc + i * 16 + l15) * 64 + kb);
            }
            #pragma unroll
            for (int i = 0; i < 4; ++i)
                #pragma unroll
                for (int j = 0; j < 4; ++j)
                    acc[i][j] = __builtin_amdgcn_mfma_f32_16x16x32_bf16(af[i], bfr[j], acc[i][j], 0, 0, 0);
        }
        __syncthreads();
    }

    float* outp = scoresP + ((size_t)(kc * NB + n) * MMID) * MMID;
    const int colb = n0 + wc + l15;
    const int rowb = m0 + wr + l16 * 4;
    #pragma unroll
    for (int i = 0; i < 4; ++i)
        #pragma unroll
        for (int r = 0; r < 4; ++r) {
            const int row = rowb + i * 16 + r;
            #pragma unroll
            for (int j = 0; j < 4; ++j)
                outp[(size_t)row * MMID + colb + j * 16] = acc[i][j][r];
        }
}

// ---------- softmax over rows (reduces KSPLIT partials, scale 1/64) ----------
__global__ __launch_bounds__(64) void softmax_rows(
    const float* __restrict__ scoresP, unsigned short* __restrict__ attn)
{
    const size_t row = blockIdx.x;            // n*256 + m
    const int l = threadIdx.x;
    const size_t pstride = (size_t)NB * MMID * MMID;
    float4 v = {0.f, 0.f, 0.f, 0.f};
    #pragma unroll
    for (int p = 0; p < KSPLIT; ++p) {
        float4 u = *(const float4*)(scoresP + p * pstride + row * MMID + l * 4);
        v.x += u.x; v.y += u.y; v.z += u.z; v.w += u.w;
    }
    float mx = fmaxf(fmaxf(v.x, v.y), fmaxf(v.z, v.w));
    #pragma unroll
    for (int off = 32; off; off >>= 1) mx = fmaxf(mx, __shfl_xor(mx, off));
    const float sc = 0.015625f;               // 1/64
    float e0 = __expf((v.x - mx) * sc), e1 = __expf((v.y - mx) * sc);
    float e2 = __expf((v.z - mx) * sc), e3 = __expf((v.w - mx) * sc);
    float sum = e0 + e1 + e2 + e3;
    #pragma unroll
    for (int off = 32; off; off >>= 1) sum += __shfl_xor(sum, off);
    const float inv = 1.0f / sum;
    unsigned short o[4] = { f2b(e0 * inv), f2b(e1 * inv), f2b(e2 * inv), f2b(e3 * inv) };
    *(uint64_t*)(attn + row * MMID + l * 4) = *(const uint64_t*)o;
}

// ---------- NT GEMM: D[m][n] = sum_k A[m][k] * B[n][k] ----------
// EPI: 0 = +bias[row], bf16 store; 1 = f32 store; 2 = bf16 store; 3 = +bias[row]+resid, f32 store
template <int EPI>
__global__ __launch_bounds__(256) void gemm_nt(
    const unsigned short* __restrict__ A, const unsigned short* __restrict__ B,
    int lda, int ldb, int K,
    long long strideA, long long strideB,
    const float* __restrict__ bias,
    const float* __restrict__ resid,
    void* __restrict__ Cout, int ldc, long long strideC)
{
    __shared__ unsigned short As[128 * 64];
    __shared__ unsigned short Bs[128 * 64];

    const int n  = blockIdx.z;
    const int m0 = blockIdx.y * 128;
    const int n0 = blockIdx.x * 128;

    const unsigned short* Ab = A + (size_t)n * strideA + (size_t)m0 * lda;
    const unsigned short* Bb = B + (size_t)n * strideB + (size_t)n0 * ldb;

    const int t    = threadIdx.x;
    const int lane = t & 63;
    const int wave = t >> 6;
    const int wr   = (wave >> 1) * 64;
    const int wc   = (wave & 1) * 64;
    const int l15  = lane & 15;
    const int l16  = lane >> 4;

    f32x4_t acc[4][4] = {};

    for (int k0 = 0; k0 < K; k0 += 64) {
        #pragma unroll
        for (int c = 0; c < 4; ++c) {
            const int o   = (c * 256 + t) * 16;
            const int row = o >> 7;
            const int ce  = (o & 127) >> 1;
            __builtin_amdgcn_global_load_lds(
                AS1(Ab + (size_t)row * lda + k0 + ce), AS3((char*)As + o), 16, 0, 0);
            __builtin_amdgcn_global_load_lds(
                AS1(Bb + (size_t)row * ldb + k0 + ce), AS3((char*)Bs + o), 16, 0, 0);
        }
        asm volatile("s_waitcnt vmcnt(0)" ::: "memory");
        __syncthreads();

        #pragma unroll
        for (int ks = 0; ks < 2; ++ks) {
            bf16x8_t af[4], bfr[4];
            const int kb = ks * 32 + l16 * 8;
            #pragma unroll
            for (int i = 0; i < 4; ++i) {
                af[i]  = *(const bf16x8_t*)(As + (wr + i * 16 + l15) * 64 + kb);
                bfr[i] = *(const bf16x8_t*)(Bs + (wc + i * 16 + l15) * 64 + kb);
            }
            #pragma unroll
            for (int i = 0; i < 4; ++i)
                #pragma unroll
                for (int j = 0; j < 4; ++j)
                    acc[i][j] = __builtin_amdgcn_mfma_f32_16x16x32_bf16(af[i], bfr[j], acc[i][j], 0, 0, 0);
        }
        __syncthreads();
    }

    // epilogue: C/D layout col = lane&15, row = (lane>>4)*4 + r  [m89-verified]
    const int colb = n0 + wc + l15;
    const int rowb = m0 + wr + l16 * 4;
    #pragma unroll
    for (int i = 0; i < 4; ++i) {
        #pragma unroll
        for (int r = 0; r < 4; ++r) {
            const int row = rowb + i * 16 + r;
            float badd = 0.f;
            if constexpr (EPI == 0 || EPI == 3) badd = bias[row];
            #pragma unroll
            for (int j = 0; j < 4; ++j) {
                const int col = colb + j * 16;
                float v = acc[i][j][r] + badd;
                const size_t idx = (size_t)n * strideC + (size_t)row * ldc + col;
                if constexpr (EPI == 3) {
                    ((float*)Cout)[idx] = v + resid[idx];
                } else if constexpr (EPI == 1) {
                    ((float*)Cout)[idx] = v;
                } else {
                    ((unsigned short*)Cout)[idx] = f2b(v);
                }
            }
        }
    }
}

// ---------- launch ----------
extern "C" void kernel_launch(void* const* d_in, const int* in_sizes, int n_in,
                              void* d_out, int out_size, void* d_ws, size_t ws_size,
                              hipStream_t stream)
{
    const float* x   = (const float*)d_in[0];
    const float* Ws  = (const float*)d_in[1];
    const float* bs  = (const float*)d_in[2];
    const float* Wp  = (const float*)d_in[3];
    const float* bp  = (const float*)d_in[4];
    const float* Wef = (const float*)d_in[5];
    const float* be  = (const float*)d_in[6];
    float* out = (float*)d_out;

    // workspace carve-up
    unsigned short* xT     = (unsigned short*)d_ws;                       // [16][4096][512] bf16
    unsigned short* Ysp    = xT     + (size_t)NB * HW * CIN;              // [16][512][4096] bf16 (state|proj)
    unsigned short* xprojT = Ysp    + (size_t)NB * CIN * HW;              // [16][4096][256] bf16
    unsigned short* Wsp    = xprojT + (size_t)NB * HW * MMID;             // [512][512] bf16
    unsigned short* Wex    = Wsp    + (size_t)CIN * CIN;                  // [512][256] bf16
    unsigned short* attn   = Wex    + (size_t)CIN * MMID;                 // [16][256][256] bf16
    unsigned short* attnT  = attn   + (size_t)NB * MMID * MMID;           // [16][256][256] bf16
    unsigned short* G      = attnT  + (size_t)NB * MMID * MMID;           // [16][512][256] bf16
    float* bsp = (float*)(G + (size_t)NB * CIN * MMID);                   // [512]
    // scores partials alias the xT region (xT dead after gemm<0>; 33.6MB <= 67MB)
    float* scoresP = (float*)xT;                                          // [8][16][256][256] f32

    prep_weights<<<512, 256, 0, stream>>>(Ws, Wp, Wef, bs, bp, Wsp, Wex, bsp);

    // x -> xT (bf16, [h][c])
    transpose_convert_x<<<dim3(HW / 64, CIN / 64, NB), 256, 0, stream>>>(x, xT);

    // Ysp[mm][h] = Wsp[mm][c] . xT[h][c] + bsp[mm]   (M=512, N=4096, K=512)
    gemm_nt<0><<<dim3(HW / 128, CIN / 128, NB), 256, 0, stream>>>(
        Wsp, xT, CIN, CIN, CIN, 0LL, (long long)HW * CIN,
        bsp, nullptr, Ysp, HW, (long long)CIN * HW);

    // x_projT[h][k] = transpose of Ysp proj half
    transpose_bf16_64<<<dim3(HW / 64, MMID / 64, NB), 256, 0, stream>>>(
        Ysp + (size_t)MMID * HW, xprojT, HW, MMID,
        (long long)CIN * HW, (long long)HW * MMID);

    // scores partials, split-K=8  (512 blocks)
    gemm_scores<<<dim3(MMID / 128, MMID / 128, NB * KSPLIT), 256, 0, stream>>>(Ysp, scoresP);

    // attn = softmax(sum_p scoresP / 64) rows, bf16
    softmax_rows<<<NB * MMID, 64, 0, stream>>>(scoresP, attn);

    // attnT[k][m] = attn[m][k]
    transpose_bf16_64<<<dim3(MMID / 64, MMID / 64, NB), 256, 0, stream>>>(
        attn, attnT, MMID, MMID, (long long)MMID * MMID, (long long)MMID * MMID);

    // G[c][k] = Wex[c][m] . attnT[k][m]   (M=512, N=256, K=256) — (W_extend @ attn)
    gemm_nt<2><<<dim3(MMID / 128, CIN / 128, NB), 256, 0, stream>>>(
        Wex, attnT, MMID, MMID, MMID,
        0LL, (long long)MMID * MMID,
        nullptr, nullptr, G, MMID, (long long)CIN * MMID);

    // out[c][h] = G[c][k] . xprojT[h][k] + be[c] + x[c][h]   (M=512, N=4096, K=256)
    gemm_nt<3><<<dim3(HW / 128, CIN / 128, NB), 256, 0, stream>>>(
        G, xprojT, MMID, MMID, MMID,
        (long long)CIN * MMID, (long long)HW * MMID,
        be, x, out, HW, (long long)CIN * HW);
}